// Round 8
// baseline (386.520 us; speedup 1.0000x reference)
//
#include <hip/hip_runtime.h>
#include <hip/hip_bf16.h>

#define NNODES 100000
#define NEDGES 640000
#define DIM 128
#define GS 16
#define EB 128                                 // edges per block (2 per thread)
#define NSCAN_BLOCKS ((NNODES + 255) / 256)    // 391
#define G1_BLOCKS ((NNODES + 63) / 64)         // 1563 (tail block: 32 rows)

typedef __attribute__((ext_vector_type(8))) short short8;
typedef __attribute__((ext_vector_type(4))) float f32x4;

__device__ __forceinline__ ushort f2bf(float f) {
    __hip_bfloat16 h = __float2bfloat16(f);
    return *reinterpret_cast<ushort*>(&h);
}
__device__ __forceinline__ float bf2f(ushort u) {
    union { unsigned int i; float f; } v; v.i = ((unsigned int)u) << 16; return v.f;
}

// ---------------------------------------------------------------- zero init
__global__ void zero_kernel(float* __restrict__ out, int* __restrict__ hist) {
    long step = (long)gridDim.x * blockDim.x;
    long i0 = (long)blockIdx.x * blockDim.x + threadIdx.x;
    const long total = (long)NNODES * DIM;
    for (long i = i0; i < total; i += step) out[i] = 0.f;
    for (long i = i0; i < NNODES; i += step) hist[i] = 0;
}

// ---------------------------------------------------------------- node GEMM1 (MFMA)
// xab[n][0:256] = x[n][0:128] @ [W1a | W1b]  (bf16 output)
__global__ __launch_bounds__(256) void node_gemm1(const float* __restrict__ x,
                                                  const float* __restrict__ W1,
                                                  ushort* __restrict__ xab) {
    __shared__ __align__(16) char xt[64 * 256];   // 64 rows x 128 bf16, XOR-swizzled
    const int tid  = threadIdx.x;
    const int lane = tid & 63;
    const int w    = tid >> 6;
    const int lr   = lane & 15;
    const int lg   = lane >> 4;
    const int m0   = blockIdx.x * 64;
    const int mtMax = (m0 + 64 <= NNODES) ? 4 : 2;

    const int koff = (w >= 2) ? 128 : 0;
    short8 bfrag[4][4];
    #pragma unroll
    for (int nt = 0; nt < 4; ++nt) {
        const int cc = (w & 1) * 64 + nt * 16 + lr;
        #pragma unroll
        for (int kt = 0; kt < 4; ++kt) {
            const int kb = koff + kt * 32 + lg * 8;
            short8 f;
            #pragma unroll
            for (int j = 0; j < 8; ++j) f[j] = (short)f2bf(W1[(long)(kb + j) * DIM + cc]);
            bfrag[nt][kt] = f;
        }
    }

    {
        const int r  = tid >> 2;
        const int kq = (tid & 3) * 32;
        if (m0 + r < NNODES) {
            const float* xr = &x[(long)(m0 + r) * DIM + kq];
            ushort tmp[32];
            #pragma unroll
            for (int j = 0; j < 32; ++j) tmp[j] = f2bf(xr[j]);
            #pragma unroll
            for (int i = 0; i < 4; ++i) {
                int byte = r * 256 + kq * 2 + i * 16;
                byte ^= (r & 7) << 4;
                *(short8*)(xt + byte) = *(short8*)&tmp[i * 8];
            }
        }
    }
    __syncthreads();

    const int colBase = w * 64;
    for (int mt = 0; mt < mtMax; ++mt) {
        short8 afrag[4];
        #pragma unroll
        for (int kt = 0; kt < 4; ++kt) {
            const int row = mt * 16 + lr;
            int byte = row * 256 + (kt * 4 + lg) * 16;
            byte ^= (row & 7) << 4;
            afrag[kt] = *(short8*)(xt + byte);
        }
        f32x4 acc[4] = {};
        #pragma unroll
        for (int nt = 0; nt < 4; ++nt)
            #pragma unroll
            for (int kt = 0; kt < 4; ++kt)
                acc[nt] = __builtin_amdgcn_mfma_f32_16x16x32_bf16(afrag[kt], bfrag[nt][kt], acc[nt], 0, 0, 0);
        #pragma unroll
        for (int nt = 0; nt < 4; ++nt) {
            const int col = colBase + nt * 16 + lr;
            #pragma unroll
            for (int r = 0; r < 4; ++r) {
                const int row = m0 + mt * 16 + lg * 4 + r;
                xab[(long)row * 256 + col] = f2bf(acc[nt][r]);
            }
        }
    }
}

// ---------------------------------------------------------------- histogram
__global__ void hist_kernel(const int* __restrict__ ei, int* __restrict__ hist) {
    int e = blockIdx.x * 256 + threadIdx.x;
    if (e < NEDGES) atomicAdd(&hist[ei[NEDGES + e]], 1);
}

// ---------------------------------------------------------------- 2-level scan
__global__ void scan1_kernel(const int* __restrict__ hist, int* __restrict__ excl,
                             int* __restrict__ bsums) {
    __shared__ int s[256];
    int tid = threadIdx.x;
    int i = blockIdx.x * 256 + tid;
    int v = (i < NNODES) ? hist[i] : 0;
    s[tid] = v;
    __syncthreads();
    for (int o = 1; o < 256; o <<= 1) {
        int t = (tid >= o) ? s[tid - o] : 0;
        __syncthreads();
        s[tid] += t;
        __syncthreads();
    }
    if (i < NNODES) excl[i] = s[tid] - v;
    if (tid == 255) bsums[blockIdx.x] = s[255];
}

__global__ void scan2_kernel(int* __restrict__ bsums) {
    __shared__ int s[512];
    int tid = threadIdx.x;
    int v = (tid < NSCAN_BLOCKS) ? bsums[tid] : 0;
    s[tid] = v;
    __syncthreads();
    for (int o = 1; o < 512; o <<= 1) {
        int t = (tid >= o) ? s[tid - o] : 0;
        __syncthreads();
        s[tid] += t;
        __syncthreads();
    }
    if (tid < NSCAN_BLOCKS) bsums[tid] = s[tid] - v;   // exclusive
}

__global__ void scan3_kernel(const int* __restrict__ excl, const int* __restrict__ bsums,
                             int* __restrict__ cursor) {
    int i = blockIdx.x * 256 + threadIdx.x;
    if (i < NNODES) cursor[i] = excl[i] + bsums[blockIdx.x];
}

// ---------------------------------------------------------------- scatter (counting sort)
__global__ void scatter_kernel(const int* __restrict__ ei, int* __restrict__ cursor,
                               int* __restrict__ sorted) {
    int e = blockIdx.x * 256 + threadIdx.x;
    if (e < NEDGES) {
        int d = ei[NEDGES + e];
        int pos = atomicAdd(&cursor[d], 1);
        sorted[pos] = e;
    }
}

// ---------------------------------------------------------------- edge phase
// 2 edges/thread; packed+skewed constant tables; one-pass GN; segmented walk
__global__ __launch_bounds__(256) void edge_silu_kernel(
    const ushort* __restrict__ xab,
    const int* __restrict__ ei, const float* __restrict__ ea,
    const int* __restrict__ sorted,
    const float* __restrict__ W1, const float* __restrict__ b1,
    const float* __restrict__ gamma, const float* __restrict__ beta,
    float* __restrict__ out)
{
    __shared__ __align__(16) ushort ssilu[EB * 128];   // 32 KB bf16, XOR-swizzled rows
    __shared__ __align__(16) float4 w1ct[132];         // skewed idx p = c + (c>>5)
    __shared__ float sbb1[132], sgam[132], sbet[132];  // same skew
    __shared__ int   sdst[EB], ssrc[EB];
    __shared__ float4 sea4[EB];

    const int tid = threadIdx.x;
    const int e0 = blockIdx.x * EB;

    if (tid < 128) {
        int id = sorted[e0 + tid];
        sdst[tid] = ei[NEDGES + id];
        ssrc[tid] = ei[id];
        sea4[tid] = *(const float4*)&ea[(long)id * 4];
        int c = tid;
        int p = c + (c >> 5);
        w1ct[p] = make_float4(W1[256 * DIM + c], W1[257 * DIM + c],
                              W1[258 * DIM + c], W1[259 * DIM + c]);
        sbb1[p] = b1[c]; sgam[p] = gamma[c]; sbet[p] = beta[c];
    }
    __syncthreads();

    // h-phase: thread owns edges eA = tid>>2 and eA+64, channels [q*32, q*32+32)
    {
        const int eA = tid >> 2;
        const int eBt = eA + 64;
        const int q = tid & 3;
        const int c0 = q * 32;
        const int pBase = c0 + q;                        // skewed base
        const ushort* xaA = &xab[(long)sdst[eA] * 256 + c0];
        const ushort* xbA = &xab[(long)ssrc[eA] * 256 + 128 + c0];
        const ushort* xaB = &xab[(long)sdst[eBt] * 256 + c0];
        const ushort* xbB = &xab[(long)ssrc[eBt] * 256 + 128 + c0];
        const float4 aA = sea4[eA], aB = sea4[eBt];

        float vA[32], vB[32];
        #pragma unroll
        for (int i = 0; i < 4; ++i) {
            short8 gaA = *(const short8*)&xaA[i * 8];
            short8 gbA = *(const short8*)&xbA[i * 8];
            short8 gaB = *(const short8*)&xaB[i * 8];
            short8 gbB = *(const short8*)&xbB[i * 8];
            #pragma unroll
            for (int j = 0; j < 8; ++j) {
                const int idx = i * 8 + j;
                const float4 w = w1ct[pBase + idx];
                const float bb = sbb1[pBase + idx];
                float base = bb;
                float tA = base + aA.x * w.x + aA.y * w.y + aA.z * w.z + aA.w * w.w;
                float tB = base + aB.x * w.x + aB.y * w.y + aB.z * w.z + aB.w * w.w;
                vA[idx] = tA + bf2f((ushort)gaA[j]) + bf2f((ushort)gbA[j]);
                vB[idx] = tB + bf2f((ushort)gaB[j]) + bf2f((ushort)gbB[j]);
            }
        }

        // GroupNorm (one-pass stats) + SiLU for both edges; 2 groups of 16 per thread
        #pragma unroll
        for (int g = 0; g < 2; ++g) {
            float sA = 0.f, qA = 0.f, sB = 0.f, qB = 0.f;
            #pragma unroll
            for (int i = 0; i < GS; ++i) {
                float a = vA[g * GS + i], b = vB[g * GS + i];
                sA += a; qA += a * a;
                sB += b; qB += b * b;
            }
            const float mA = sA * (1.f / GS), mB = sB * (1.f / GS);
            const float varA = qA * (1.f / GS) - mA * mA;
            const float varB = qB * (1.f / GS) - mB * mB;
            const float iA = rsqrtf(varA + 1e-5f), iB = rsqrtf(varB + 1e-5f);
            #pragma unroll
            for (int i = 0; i < GS; ++i) {
                const int idx = g * GS + i;
                const float gm = sgam[pBase + idx], bt = sbet[pBase + idx];
                float tA = (vA[idx] - mA) * iA * gm + bt;
                float tB = (vB[idx] - mB) * iB * gm + bt;
                vA[idx] = tA / (1.f + __expf(-tA));
                vB[idx] = tB / (1.f + __expf(-tB));
            }
        }

        // store both edges' silu as bf16, swizzled rows
        ushort tA[32], tB[32];
        #pragma unroll
        for (int j = 0; j < 32; ++j) { tA[j] = f2bf(vA[j]); tB[j] = f2bf(vB[j]); }
        #pragma unroll
        for (int i = 0; i < 4; ++i) {
            int byteA = (eA * 256 + (c0 + i * 8) * 2) ^ ((eA & 7) << 4);
            int byteB = (eBt * 256 + (c0 + i * 8) * 2) ^ ((eBt & 7) << 4);
            *(short8*)((char*)ssilu + byteA) = *(short8*)&tA[i * 8];
            *(short8*)((char*)ssilu + byteB) = *(short8*)&tB[i * 8];
        }
    }
    __syncthreads();

    // segmented column-walk: thread = (channel c, half h of 64 edges); lane-uniform branch
    {
        const int c = tid & 127;
        const int h = tid >> 7;
        const int eS = h * 64, eE = eS + 64;
        float r = 0.f;
        int cur = sdst[eS];
        for (int ee = eS; ee < eE; ++ee) {
            int d = sdst[ee];
            if (d != cur) {
                unsafeAtomicAdd(&out[(long)cur * DIM + c], r);
                r = 0.f; cur = d;
            }
            int byte = (ee * 256 + c * 2) ^ ((ee & 7) << 4);
            r += bf2f(*(const ushort*)((const char*)ssilu + byte));
        }
        unsafeAtomicAdd(&out[(long)cur * DIM + c], r);
    }
}

// ---------------------------------------------------------------- node GEMM2 (MFMA, in-place)
__global__ __launch_bounds__(256) void node_gemm2(float* __restrict__ out,
                                                  const float* __restrict__ W2,
                                                  const float* __restrict__ b2,
                                                  const int* __restrict__ hist) {
    __shared__ __align__(16) char at[64 * 256];
    __shared__ float sb2[128];
    __shared__ int scnt[64];
    const int tid  = threadIdx.x;
    const int lane = tid & 63;
    const int w    = tid >> 6;
    const int lr   = lane & 15;
    const int lg   = lane >> 4;
    const int m0   = blockIdx.x * 64;
    const int mtMax = (m0 + 64 <= NNODES) ? 4 : 2;

    short8 bfrag[2][4];
    #pragma unroll
    for (int nt = 0; nt < 2; ++nt) {
        const int cc = w * 32 + nt * 16 + lr;
        #pragma unroll
        for (int kt = 0; kt < 4; ++kt) {
            const int kb = kt * 32 + lg * 8;
            short8 f;
            #pragma unroll
            for (int j = 0; j < 8; ++j) f[j] = (short)f2bf(W2[(long)(kb + j) * DIM + cc]);
            bfrag[nt][kt] = f;
        }
    }

    if (tid < 128) sb2[tid] = b2[tid];
    if (tid < 64 && m0 + tid < NNODES) scnt[tid] = hist[m0 + tid];

    {
        const int r  = tid >> 2;
        const int kq = (tid & 3) * 32;
        if (m0 + r < NNODES) {
            const float* ar = &out[(long)(m0 + r) * DIM + kq];
            ushort tmp[32];
            #pragma unroll
            for (int j = 0; j < 32; ++j) tmp[j] = f2bf(ar[j]);
            #pragma unroll
            for (int i = 0; i < 4; ++i) {
                int byte = r * 256 + kq * 2 + i * 16;
                byte ^= (r & 7) << 4;
                *(short8*)(at + byte) = *(short8*)&tmp[i * 8];
            }
        }
    }
    __syncthreads();

    for (int mt = 0; mt < mtMax; ++mt) {
        short8 afrag[4];
        #pragma unroll
        for (int kt = 0; kt < 4; ++kt) {
            const int row = mt * 16 + lr;
            int byte = row * 256 + (kt * 4 + lg) * 16;
            byte ^= (row & 7) << 4;
            afrag[kt] = *(short8*)(at + byte);
        }
        f32x4 acc[2] = {};
        #pragma unroll
        for (int nt = 0; nt < 2; ++nt)
            #pragma unroll
            for (int kt = 0; kt < 4; ++kt)
                acc[nt] = __builtin_amdgcn_mfma_f32_16x16x32_bf16(afrag[kt], bfrag[nt][kt], acc[nt], 0, 0, 0);
        #pragma unroll
        for (int nt = 0; nt < 2; ++nt) {
            const int col = w * 32 + nt * 16 + lr;
            #pragma unroll
            for (int r = 0; r < 4; ++r) {
                const int rr = mt * 16 + lg * 4 + r;
                float cnt = (float)scnt[rr];
                float sc = 1.f / fmaxf(cnt, 1.f);
                out[(long)(m0 + rr) * DIM + col] = (acc[nt][r] + cnt * sb2[col]) * sc;
            }
        }
    }
}

// ---------------------------------------------------------------- launch
extern "C" void kernel_launch(void* const* d_in, const int* in_sizes, int n_in,
                              void* d_out, int out_size, void* d_ws, size_t ws_size,
                              hipStream_t stream) {
    const float* x     = (const float*)d_in[0];
    const int*   ei    = (const int*)  d_in[1];
    const float* ea    = (const float*)d_in[2];
    const float* W1    = (const float*)d_in[3];
    const float* b1    = (const float*)d_in[4];
    const float* gamma = (const float*)d_in[5];
    const float* beta  = (const float*)d_in[6];
    const float* W2    = (const float*)d_in[7];
    const float* b2    = (const float*)d_in[8];
    float* out = (float*)d_out;

    char* ws = (char*)d_ws;
    size_t off = 0;
    ushort* xab   = (ushort*)(ws + off); off += (size_t)NNODES * 256 * sizeof(ushort);
    int*    hist  = (int*)   (ws + off); off += (size_t)NNODES * sizeof(int);
    int*    excl  = (int*)   (ws + off); off += (size_t)NNODES * sizeof(int);
    int*    cursor= (int*)   (ws + off); off += (size_t)NNODES * sizeof(int);
    int*    bsums = (int*)   (ws + off); off += 512 * sizeof(int);
    int*    sorted= (int*)   (ws + off); off += (size_t)NEDGES * sizeof(int);

    zero_kernel<<<2048, 256, 0, stream>>>(out, hist);
    node_gemm1<<<G1_BLOCKS, 256, 0, stream>>>(x, W1, xab);
    hist_kernel<<<(NEDGES + 255) / 256, 256, 0, stream>>>(ei, hist);
    scan1_kernel<<<NSCAN_BLOCKS, 256, 0, stream>>>(hist, excl, bsums);
    scan2_kernel<<<1, 512, 0, stream>>>(bsums);
    scan3_kernel<<<NSCAN_BLOCKS, 256, 0, stream>>>(excl, bsums, cursor);
    scatter_kernel<<<(NEDGES + 255) / 256, 256, 0, stream>>>(ei, cursor, sorted);
    edge_silu_kernel<<<NEDGES / EB, 256, 0, stream>>>(xab, ei, ea, sorted,
                                                      W1, b1, gamma, beta, out);
    node_gemm2<<<G1_BLOCKS, 256, 0, stream>>>(out, W2, b2, hist);
}

// Round 9
// 228.192 us; speedup vs baseline: 1.6938x; 1.6938x over previous
//
#include <hip/hip_runtime.h>
#include <hip/hip_bf16.h>

#define NNODES 100000
#define NEDGES 640000
#define DIM 128
#define GS 16
#define EB 64                                  // edges per block (1 per thread)
#define NSCAN_BLOCKS ((NNODES + 255) / 256)    // 391
#define G1_BLOCKS ((NNODES + 63) / 64)         // 1563 (tail block: 32 rows)

typedef __attribute__((ext_vector_type(8))) short short8;
typedef __attribute__((ext_vector_type(4))) float f32x4;

__device__ __forceinline__ ushort f2bf(float f) {
    __hip_bfloat16 h = __float2bfloat16(f);
    return *reinterpret_cast<ushort*>(&h);
}
__device__ __forceinline__ float bf2f(ushort u) {
    union { unsigned int i; float f; } v; v.i = ((unsigned int)u) << 16; return v.f;
}

// ---------------------------------------------------------------- zero init
__global__ void zero_kernel(float* __restrict__ out, int* __restrict__ hist) {
    long step = (long)gridDim.x * blockDim.x;
    long i0 = (long)blockIdx.x * blockDim.x + threadIdx.x;
    const long total = (long)NNODES * DIM;
    for (long i = i0; i < total; i += step) out[i] = 0.f;
    for (long i = i0; i < NNODES; i += step) hist[i] = 0;
}

// ---------------------------------------------------------------- node GEMM1 (MFMA)
// xab[n][0:256] = x[n][0:128] @ [W1a | W1b]  (bf16 output)
__global__ __launch_bounds__(256) void node_gemm1(const float* __restrict__ x,
                                                  const float* __restrict__ W1,
                                                  ushort* __restrict__ xab) {
    __shared__ __align__(16) char xt[64 * 256];   // 64 rows x 128 bf16, XOR-swizzled
    const int tid  = threadIdx.x;
    const int lane = tid & 63;
    const int w    = tid >> 6;
    const int lr   = lane & 15;
    const int lg   = lane >> 4;
    const int m0   = blockIdx.x * 64;
    const int mtMax = (m0 + 64 <= NNODES) ? 4 : 2;

    const int koff = (w >= 2) ? 128 : 0;
    short8 bfrag[4][4];
    #pragma unroll
    for (int nt = 0; nt < 4; ++nt) {
        const int cc = (w & 1) * 64 + nt * 16 + lr;
        #pragma unroll
        for (int kt = 0; kt < 4; ++kt) {
            const int kb = koff + kt * 32 + lg * 8;
            short8 f;
            #pragma unroll
            for (int j = 0; j < 8; ++j) f[j] = (short)f2bf(W1[(long)(kb + j) * DIM + cc]);
            bfrag[nt][kt] = f;
        }
    }

    {
        const int r  = tid >> 2;
        const int kq = (tid & 3) * 32;
        if (m0 + r < NNODES) {
            const float* xr = &x[(long)(m0 + r) * DIM + kq];
            ushort tmp[32];
            #pragma unroll
            for (int j = 0; j < 32; ++j) tmp[j] = f2bf(xr[j]);
            #pragma unroll
            for (int i = 0; i < 4; ++i) {
                int byte = r * 256 + kq * 2 + i * 16;
                byte ^= (r & 7) << 4;
                *(short8*)(xt + byte) = *(short8*)&tmp[i * 8];
            }
        }
    }
    __syncthreads();

    const int colBase = w * 64;
    for (int mt = 0; mt < mtMax; ++mt) {
        short8 afrag[4];
        #pragma unroll
        for (int kt = 0; kt < 4; ++kt) {
            const int row = mt * 16 + lr;
            int byte = row * 256 + (kt * 4 + lg) * 16;
            byte ^= (row & 7) << 4;
            afrag[kt] = *(short8*)(xt + byte);
        }
        f32x4 acc[4] = {};
        #pragma unroll
        for (int nt = 0; nt < 4; ++nt)
            #pragma unroll
            for (int kt = 0; kt < 4; ++kt)
                acc[nt] = __builtin_amdgcn_mfma_f32_16x16x32_bf16(afrag[kt], bfrag[nt][kt], acc[nt], 0, 0, 0);
        #pragma unroll
        for (int nt = 0; nt < 4; ++nt) {
            const int col = colBase + nt * 16 + lr;
            #pragma unroll
            for (int r = 0; r < 4; ++r) {
                const int row = m0 + mt * 16 + lg * 4 + r;
                xab[(long)row * 256 + col] = f2bf(acc[nt][r]);
            }
        }
    }
}

// ---------------------------------------------------------------- histogram
__global__ void hist_kernel(const int* __restrict__ ei, int* __restrict__ hist) {
    int e = blockIdx.x * 256 + threadIdx.x;
    if (e < NEDGES) atomicAdd(&hist[ei[NEDGES + e]], 1);
}

// ---------------------------------------------------------------- 2-level scan
__global__ void scan1_kernel(const int* __restrict__ hist, int* __restrict__ excl,
                             int* __restrict__ bsums) {
    __shared__ int s[256];
    int tid = threadIdx.x;
    int i = blockIdx.x * 256 + tid;
    int v = (i < NNODES) ? hist[i] : 0;
    s[tid] = v;
    __syncthreads();
    for (int o = 1; o < 256; o <<= 1) {
        int t = (tid >= o) ? s[tid - o] : 0;
        __syncthreads();
        s[tid] += t;
        __syncthreads();
    }
    if (i < NNODES) excl[i] = s[tid] - v;
    if (tid == 255) bsums[blockIdx.x] = s[255];
}

__global__ void scan2_kernel(int* __restrict__ bsums) {
    __shared__ int s[512];
    int tid = threadIdx.x;
    int v = (tid < NSCAN_BLOCKS) ? bsums[tid] : 0;
    s[tid] = v;
    __syncthreads();
    for (int o = 1; o < 512; o <<= 1) {
        int t = (tid >= o) ? s[tid - o] : 0;
        __syncthreads();
        s[tid] += t;
        __syncthreads();
    }
    if (tid < NSCAN_BLOCKS) bsums[tid] = s[tid] - v;   // exclusive
}

__global__ void scan3_kernel(const int* __restrict__ excl, const int* __restrict__ bsums,
                             int* __restrict__ cursor) {
    int i = blockIdx.x * 256 + threadIdx.x;
    if (i < NNODES) cursor[i] = excl[i] + bsums[blockIdx.x];
}

// ---------------------------------------------------------------- scatter (counting sort)
__global__ void scatter_kernel(const int* __restrict__ ei, int* __restrict__ cursor,
                               int* __restrict__ sorted) {
    int e = blockIdx.x * 256 + threadIdx.x;
    if (e < NEDGES) {
        int d = ei[NEDGES + e];
        int pos = atomicAdd(&cursor[d], 1);
        sorted[pos] = e;
    }
}

// ---------------------------------------------------------------- edge phase
// 1 edge/thread (EB=64); packed+skewed constants; one-pass GN; segmented walk
__global__ __launch_bounds__(256) void edge_silu_kernel(
    const ushort* __restrict__ xab,
    const int* __restrict__ ei, const float* __restrict__ ea,
    const int* __restrict__ sorted,
    const float* __restrict__ W1, const float* __restrict__ b1,
    const float* __restrict__ gamma, const float* __restrict__ beta,
    float* __restrict__ out)
{
    __shared__ __align__(16) ushort ssilu[EB * 128];   // 16 KB bf16, XOR-swizzled rows
    __shared__ __align__(16) float4 w1ct[132];         // skewed idx p = c + (c>>5)
    __shared__ float sbb1[132], sgam[132], sbet[132];  // same skew
    __shared__ int   sdst[EB], ssrc[EB];
    __shared__ float4 sea4[EB];

    const int tid = threadIdx.x;
    const int e0 = blockIdx.x * EB;

    if (tid < EB) {
        int id = sorted[e0 + tid];
        sdst[tid] = ei[NEDGES + id];
        ssrc[tid] = ei[id];
        sea4[tid] = *(const float4*)&ea[(long)id * 4];
    }
    if (tid < 128) {
        int c = tid;
        int p = c + (c >> 5);
        w1ct[p] = make_float4(W1[256 * DIM + c], W1[257 * DIM + c],
                              W1[258 * DIM + c], W1[259 * DIM + c]);
        sbb1[p] = b1[c]; sgam[p] = gamma[c]; sbet[p] = beta[c];
    }
    __syncthreads();

    // h-phase: thread owns edge e = tid>>2, channels [q*32, q*32+32)
    {
        const int e = tid >> 2;
        const int q = tid & 3;
        const int c0 = q * 32;
        const int pBase = c0 + q;                        // skewed base
        const ushort* xaRow = &xab[(long)sdst[e] * 256 + c0];
        const ushort* xbRow = &xab[(long)ssrc[e] * 256 + 128 + c0];
        const float4 a = sea4[e];

        float v[32];
        #pragma unroll
        for (int i = 0; i < 4; ++i) {
            short8 ga = *(const short8*)&xaRow[i * 8];
            short8 gb = *(const short8*)&xbRow[i * 8];
            #pragma unroll
            for (int j = 0; j < 8; ++j) {
                const int idx = i * 8 + j;
                const float4 w = w1ct[pBase + idx];
                float t = sbb1[pBase + idx] + a.x * w.x + a.y * w.y + a.z * w.z + a.w * w.w;
                v[idx] = t + bf2f((ushort)ga[j]) + bf2f((ushort)gb[j]);
            }
        }

        // GroupNorm (one-pass stats) + SiLU; thread owns 2 full groups of 16
        #pragma unroll
        for (int g = 0; g < 2; ++g) {
            float s = 0.f, qq = 0.f;
            #pragma unroll
            for (int i = 0; i < GS; ++i) {
                float a2 = v[g * GS + i];
                s += a2; qq += a2 * a2;
            }
            const float m = s * (1.f / GS);
            const float var = qq * (1.f / GS) - m * m;
            const float inv = rsqrtf(var + 1e-5f);
            #pragma unroll
            for (int i = 0; i < GS; ++i) {
                const int idx = g * GS + i;
                const float sc = sgam[pBase + idx] * inv;
                const float off = sbet[pBase + idx] - m * sc;
                float t = v[idx] * sc + off;
                v[idx] = t / (1.f + __expf(-t));
            }
        }

        // store silu as bf16, swizzled rows
        ushort tmp[32];
        #pragma unroll
        for (int j = 0; j < 32; ++j) tmp[j] = f2bf(v[j]);
        #pragma unroll
        for (int i = 0; i < 4; ++i) {
            int byte = (e * 256 + (c0 + i * 8) * 2) ^ ((e & 7) << 4);
            *(short8*)((char*)ssilu + byte) = *(short8*)&tmp[i * 8];
        }
    }
    __syncthreads();

    // segmented column-walk: thread = (channel c, half h of 32 edges); lane-uniform branch
    {
        const int c = tid & 127;
        const int h = tid >> 7;
        const int eS = h * 32, eE = eS + 32;
        float r = 0.f;
        int cur = sdst[eS];
        for (int ee = eS; ee < eE; ++ee) {
            int d = sdst[ee];
            if (d != cur) {
                unsafeAtomicAdd(&out[(long)cur * DIM + c], r);
                r = 0.f; cur = d;
            }
            int byte = (ee * 256 + c * 2) ^ ((ee & 7) << 4);
            r += bf2f(*(const ushort*)((const char*)ssilu + byte));
        }
        unsafeAtomicAdd(&out[(long)cur * DIM + c], r);
    }
}

// ---------------------------------------------------------------- node GEMM2 (MFMA, in-place)
__global__ __launch_bounds__(256) void node_gemm2(float* __restrict__ out,
                                                  const float* __restrict__ W2,
                                                  const float* __restrict__ b2,
                                                  const int* __restrict__ hist) {
    __shared__ __align__(16) char at[64 * 256];
    __shared__ float sb2[128];
    __shared__ int scnt[64];
    const int tid  = threadIdx.x;
    const int lane = tid & 63;
    const int w    = tid >> 6;
    const int lr   = lane & 15;
    const int lg   = lane >> 4;
    const int m0   = blockIdx.x * 64;
    const int mtMax = (m0 + 64 <= NNODES) ? 4 : 2;

    short8 bfrag[2][4];
    #pragma unroll
    for (int nt = 0; nt < 2; ++nt) {
        const int cc = w * 32 + nt * 16 + lr;
        #pragma unroll
        for (int kt = 0; kt < 4; ++kt) {
            const int kb = kt * 32 + lg * 8;
            short8 f;
            #pragma unroll
            for (int j = 0; j < 8; ++j) f[j] = (short)f2bf(W2[(long)(kb + j) * DIM + cc]);
            bfrag[nt][kt] = f;
        }
    }

    if (tid < 128) sb2[tid] = b2[tid];
    if (tid < 64 && m0 + tid < NNODES) scnt[tid] = hist[m0 + tid];

    {
        const int r  = tid >> 2;
        const int kq = (tid & 3) * 32;
        if (m0 + r < NNODES) {
            const float* ar = &out[(long)(m0 + r) * DIM + kq];
            ushort tmp[32];
            #pragma unroll
            for (int j = 0; j < 32; ++j) tmp[j] = f2bf(ar[j]);
            #pragma unroll
            for (int i = 0; i < 4; ++i) {
                int byte = r * 256 + kq * 2 + i * 16;
                byte ^= (r & 7) << 4;
                *(short8*)(at + byte) = *(short8*)&tmp[i * 8];
            }
        }
    }
    __syncthreads();

    for (int mt = 0; mt < mtMax; ++mt) {
        short8 afrag[4];
        #pragma unroll
        for (int kt = 0; kt < 4; ++kt) {
            const int row = mt * 16 + lr;
            int byte = row * 256 + (kt * 4 + lg) * 16;
            byte ^= (row & 7) << 4;
            afrag[kt] = *(short8*)(at + byte);
        }
        f32x4 acc[2] = {};
        #pragma unroll
        for (int nt = 0; nt < 2; ++nt)
            #pragma unroll
            for (int kt = 0; kt < 4; ++kt)
                acc[nt] = __builtin_amdgcn_mfma_f32_16x16x32_bf16(afrag[kt], bfrag[nt][kt], acc[nt], 0, 0, 0);
        #pragma unroll
        for (int nt = 0; nt < 2; ++nt) {
            const int col = w * 32 + nt * 16 + lr;
            #pragma unroll
            for (int r = 0; r < 4; ++r) {
                const int rr = mt * 16 + lg * 4 + r;
                float cnt = (float)scnt[rr];
                float sc = 1.f / fmaxf(cnt, 1.f);
                out[(long)(m0 + rr) * DIM + col] = (acc[nt][r] + cnt * sb2[col]) * sc;
            }
        }
    }
}

// ---------------------------------------------------------------- launch
extern "C" void kernel_launch(void* const* d_in, const int* in_sizes, int n_in,
                              void* d_out, int out_size, void* d_ws, size_t ws_size,
                              hipStream_t stream) {
    const float* x     = (const float*)d_in[0];
    const int*   ei    = (const int*)  d_in[1];
    const float* ea    = (const float*)d_in[2];
    const float* W1    = (const float*)d_in[3];
    const float* b1    = (const float*)d_in[4];
    const float* gamma = (const float*)d_in[5];
    const float* beta  = (const float*)d_in[6];
    const float* W2    = (const float*)d_in[7];
    const float* b2    = (const float*)d_in[8];
    float* out = (float*)d_out;

    char* ws = (char*)d_ws;
    size_t off = 0;
    ushort* xab   = (ushort*)(ws + off); off += (size_t)NNODES * 256 * sizeof(ushort);
    int*    hist  = (int*)   (ws + off); off += (size_t)NNODES * sizeof(int);
    int*    excl  = (int*)   (ws + off); off += (size_t)NNODES * sizeof(int);
    int*    cursor= (int*)   (ws + off); off += (size_t)NNODES * sizeof(int);
    int*    bsums = (int*)   (ws + off); off += 512 * sizeof(int);
    int*    sorted= (int*)   (ws + off); off += (size_t)NEDGES * sizeof(int);

    zero_kernel<<<2048, 256, 0, stream>>>(out, hist);
    node_gemm1<<<G1_BLOCKS, 256, 0, stream>>>(x, W1, xab);
    hist_kernel<<<(NEDGES + 255) / 256, 256, 0, stream>>>(ei, hist);
    scan1_kernel<<<NSCAN_BLOCKS, 256, 0, stream>>>(hist, excl, bsums);
    scan2_kernel<<<1, 512, 0, stream>>>(bsums);
    scan3_kernel<<<NSCAN_BLOCKS, 256, 0, stream>>>(excl, bsums, cursor);
    scatter_kernel<<<(NEDGES + 255) / 256, 256, 0, stream>>>(ei, cursor, sorted);
    edge_silu_kernel<<<NEDGES / EB, 256, 0, stream>>>(xab, ei, ea, sorted,
                                                      W1, b1, gamma, beta, out);
    node_gemm2<<<G1_BLOCKS, 256, 0, stream>>>(out, W2, b2, hist);
}